// Round 3
// baseline (1008.538 us; speedup 1.0000x reference)
//
#include <hip/hip_runtime.h>
#include <stdint.h>

typedef unsigned short u16;
typedef __bf16 bf16x8 __attribute__((ext_vector_type(8)));
typedef float f32x4 __attribute__((ext_vector_type(4)));

#define N_NODES 50000
#define N_EDGES 800000
#define LN_EPS 1e-5f

// pack 8 consecutive f32 -> uint4 of 8 bf16 (RNE via hw cvt)
__device__ __forceinline__ uint4 pack8(const float* __restrict__ p) {
    const float4 f0 = ((const float4*)p)[0];
    const float4 f1 = ((const float4*)p)[1];
    union { __bf16 b[8]; uint4 q; } t;
    t.b[0] = (__bf16)f0.x; t.b[1] = (__bf16)f0.y; t.b[2] = (__bf16)f0.z; t.b[3] = (__bf16)f0.w;
    t.b[4] = (__bf16)f1.x; t.b[5] = (__bf16)f1.y; t.b[6] = (__bf16)f1.z; t.b[7] = (__bf16)f1.w;
    return t.q;
}

// ---------------- weight pre-pack (runs once per call, ~5us) ----------------
// Packed layout per source matrix: chunk t = (kb*8 + col16)*64 + lane holds
// bf16[8] = W[kb*32 + (lane>>4)*8 + j][col16*16 + (lane&15)], j=0..7.
// Segments in out: [0,6144) edge W1 (12 kb); [6144,8192) edge W2 (4 kb);
//                  [8192,12288) node W1 (8 kb); [12288,14336) node W2 (4 kb).
__global__ void pack_weights(const float* __restrict__ w1e, const float* __restrict__ w2e,
                             const float* __restrict__ w1n, const float* __restrict__ w2n,
                             uint4* __restrict__ out)
{
    const int t = blockIdx.x * 256 + threadIdx.x;
    const float* W; int idx;
    if (t < 6144)       { W = w1e; idx = t; }
    else if (t < 8192)  { W = w2e; idx = t - 6144; }
    else if (t < 12288) { W = w1n; idx = t - 8192; }
    else                { W = w2n; idx = t - 12288; }
    const int lane = idx & 63;
    const int col16 = (idx >> 6) & 7;
    const int kb = idx >> 9;
    const int row0 = kb * 32 + (lane >> 4) * 8;
    const int col = col16 * 16 + (lane & 15);
    union { __bf16 b[8]; uint4 q; } v;
#pragma unroll
    for (int j = 0; j < 8; ++j) v.b[j] = (__bf16)W[(size_t)(row0 + j) * 128 + col];
    out[t] = v.q;
}

// ---------------- Edge MLP + scatter-add ----------------
// x tile: [part(0=send,1=recv,2=elat)][64 rows][128 bf16], 16B chunks,
// XOR-swizzled within each row: stored_chunk = chunk ^ (row&7).
// After L1, part0 is overlaid by h1; LN scratch overlays part1.
__global__ __launch_bounds__(256, 3)
void edge_mlp_kernel(const float* __restrict__ node, const float* __restrict__ elat,
                     const int* __restrict__ senders, const int* __restrict__ receivers,
                     const float* __restrict__ b1, const float* __restrict__ b2,
                     const float* __restrict__ gam, const float* __restrict__ bet,
                     const uint4* __restrict__ w1p, const uint4* __restrict__ w2p,
                     float* __restrict__ eout, float* __restrict__ aggr)
{
    __shared__ __align__(16) u16 x_lds[3 * 64 * 128];   // 48 KB
    __shared__ int rcv_s[64];

    float2* part = (float2*)(x_lds + 8192);             // part1 region (dead after L1)
    float*  muv  = (float*)(x_lds + 8192 + 1024);
    float*  rsv  = (float*)(x_lds + 8192 + 1152);

    const int tid = threadIdx.x;
    const int w = tid >> 6;
    const int lane = tid & 63;
    const int cl = lane & 15;
    const int q = lane >> 4;
    const int n_base = w * 32;

    float b1v[2], b2v[2], gv[2], bv[2];
#pragma unroll
    for (int n = 0; n < 2; ++n) {
        const int c = n_base + n * 16 + cl;
        b1v[n] = b1[c]; b2v[n] = b2[c];
        gv[n]  = gam[c]; bv[n] = bet[c];
    }

    for (int tile = blockIdx.x; tile < N_EDGES / 64; tile += gridDim.x) {
        const int base = tile * 64;

        // ---- gather + f32->bf16 convert ----
        {
            const int ch = tid & 15;
            const int r0 = tid >> 4;
#pragma unroll
            for (int gp = 0; gp < 4; ++gp) {
                const int row = gp * 16 + r0;
                const int rx = row & 7;
                const int sn = senders[base + row];
                const int rc = receivers[base + row];
                if (ch == 0) rcv_s[row] = rc;
                uint4* dst = (uint4*)x_lds + row * 16;
                dst[ch ^ rx]          = pack8(node + (size_t)sn * 128 + ch * 8);
                dst[1024 + (ch ^ rx)] = pack8(node + (size_t)rc * 128 + ch * 8);
                dst[2048 + (ch ^ rx)] = pack8(elat + (size_t)(base + row) * 128 + ch * 8);
            }
        }
        __syncthreads();  // A: x tile ready

        // ---- layer 1: [64,384] x [384,128], weights streamed from L2 ----
        f32x4 acc[4][2];
#pragma unroll
        for (int m = 0; m < 4; ++m)
#pragma unroll
            for (int n = 0; n < 2; ++n)
#pragma unroll
                for (int r = 0; r < 4; ++r) acc[m][n][r] = 0.f;

        uint4 wreg[14][2];
#pragma unroll
        for (int kb = 0; kb < 2; ++kb)
#pragma unroll
            for (int n = 0; n < 2; ++n)
                wreg[kb][n] = w1p[(kb * 8 + w * 2 + n) * 64 + lane];

#pragma unroll
        for (int kb = 0; kb < 12; ++kb) {
            if (kb + 2 < 12) {
#pragma unroll
                for (int n = 0; n < 2; ++n)
                    wreg[kb + 2][n] = w1p[((kb + 2) * 8 + w * 2 + n) * 64 + lane];
            }
            const int p = kb >> 2, k2 = kb & 3;
            bf16x8 a[4];
#pragma unroll
            for (int m = 0; m < 4; ++m) {
                const int row = m * 16 + cl;
                a[m] = __builtin_bit_cast(bf16x8,
                    ((const uint4*)x_lds)[p * 1024 + row * 16 + ((k2 * 4 + q) ^ (row & 7))]);
            }
#pragma unroll
            for (int m = 0; m < 4; ++m)
#pragma unroll
                for (int n = 0; n < 2; ++n)
                    acc[m][n] = __builtin_amdgcn_mfma_f32_16x16x32_bf16(
                        a[m], __builtin_bit_cast(bf16x8, wreg[kb][n]), acc[m][n], 0, 0, 0);
        }

        // prefetch all W2 fragments (drain overlaps h-store + barrier)
        uint4 w2reg[4][2];
#pragma unroll
        for (int kb = 0; kb < 4; ++kb)
#pragma unroll
            for (int n = 0; n < 2; ++n)
                w2reg[kb][n] = w2p[(kb * 8 + w * 2 + n) * 64 + lane];

        __syncthreads();  // B: all waves done reading part0 before h overlay

        // relu + bias, h1 -> part0 region (swizzled)
        {
            __bf16* hb = (__bf16*)x_lds;
#pragma unroll
            for (int m = 0; m < 4; ++m)
#pragma unroll
                for (int n = 0; n < 2; ++n)
#pragma unroll
                    for (int r = 0; r < 4; ++r) {
                        const int row = m * 16 + q * 4 + r;
                        const int col = n_base + n * 16 + cl;
                        hb[row * 128 + (((col >> 3) ^ (row & 7)) << 3) + (col & 7)] =
                            (__bf16)fmaxf(acc[m][n][r] + b1v[n], 0.f);
                    }
        }
        __syncthreads();  // C: h ready

        // ---- layer 2: [64,128] x [128,128] ----
#pragma unroll
        for (int m = 0; m < 4; ++m)
#pragma unroll
            for (int n = 0; n < 2; ++n)
#pragma unroll
                for (int r = 0; r < 4; ++r) acc[m][n][r] = 0.f;
#pragma unroll
        for (int kb = 0; kb < 4; ++kb) {
            bf16x8 a[4];
#pragma unroll
            for (int m = 0; m < 4; ++m) {
                const int row = m * 16 + cl;
                a[m] = __builtin_bit_cast(bf16x8,
                    ((const uint4*)x_lds)[row * 16 + ((kb * 4 + q) ^ (row & 7))]);
            }
#pragma unroll
            for (int m = 0; m < 4; ++m)
#pragma unroll
                for (int n = 0; n < 2; ++n)
                    acc[m][n] = __builtin_amdgcn_mfma_f32_16x16x32_bf16(
                        a[m], __builtin_bit_cast(bf16x8, w2reg[kb][n]), acc[m][n], 0, 0, 0);
        }

#pragma unroll
        for (int m = 0; m < 4; ++m)
#pragma unroll
            for (int n = 0; n < 2; ++n)
#pragma unroll
                for (int r = 0; r < 4; ++r)
                    acc[m][n][r] = fmaxf(acc[m][n][r] + b2v[n], 0.f);

        // per-row partial sums (each wave covers 32 cols of every row)
#pragma unroll
        for (int m = 0; m < 4; ++m)
#pragma unroll
            for (int r = 0; r < 4; ++r) {
                float s  = acc[m][0][r] + acc[m][1][r];
                float ss = acc[m][0][r] * acc[m][0][r] + acc[m][1][r] * acc[m][1][r];
#pragma unroll
                for (int off = 1; off < 16; off <<= 1) {
                    s  += __shfl_xor(s, off, 64);
                    ss += __shfl_xor(ss, off, 64);
                }
                if (cl == 0) part[w * 64 + m * 16 + q * 4 + r] = make_float2(s, ss);
            }
        __syncthreads();  // D
        if (tid < 64) {
            float s = 0.f, ss = 0.f;
#pragma unroll
            for (int ww = 0; ww < 4; ++ww) { const float2 pp = part[ww * 64 + tid]; s += pp.x; ss += pp.y; }
            const float mu = s * (1.f / 128.f);
            const float var = ss * (1.f / 128.f) - mu * mu;
            muv[tid] = mu;
            rsv[tid] = rsqrtf(var + LN_EPS);
        }
        __syncthreads();  // E

        // ---- LN + scatter atomics + residual + f32 writeout ----
#pragma unroll
        for (int m = 0; m < 4; ++m)
#pragma unroll
            for (int r = 0; r < 4; ++r) {
                const int row = m * 16 + q * 4 + r;
                const float mu = muv[row];
                const float rs = rsv[row];
                const int rc = rcv_s[row];
                float* orow = eout + (size_t)(base + row) * 128;
#pragma unroll
                for (int n = 0; n < 2; ++n) {
                    const int col = n_base + n * 16 + cl;
                    const float ln = (acc[m][n][r] - mu) * rs * gv[n] + bv[n];
                    atomicAdd(&aggr[(size_t)rc * 128 + col], ln);
                    const float e = (float)((__bf16*)x_lds)[16384 + row * 128 + (((col >> 3) ^ (row & 7)) << 3) + (col & 7)];
                    orow[col] = ln + e;
                }
            }
        __syncthreads();  // F: protect x_lds/rcv_s before next gather
    }
}

// ---------------- Node MLP ----------------
// x tile: [part0=node latents][part1=aggr]; h1 overlays part1 after L1.
__global__ __launch_bounds__(256, 4)
void node_mlp_kernel(const float* __restrict__ node, const float* __restrict__ aggr,
                     const float* __restrict__ b1, const float* __restrict__ b2,
                     const float* __restrict__ gam, const float* __restrict__ bet,
                     const uint4* __restrict__ w1p, const uint4* __restrict__ w2p,
                     float* __restrict__ nout)
{
    __shared__ __align__(16) u16 x_lds[2 * 64 * 128];   // 32 KB
    __shared__ float2 part[256];
    __shared__ float muv[64], rsv[64];

    const int tid = threadIdx.x;
    const int w = tid >> 6;
    const int lane = tid & 63;
    const int cl = lane & 15;
    const int q = lane >> 4;
    const int n_base = w * 32;

    float b1v[2], b2v[2], gv[2], bv[2];
#pragma unroll
    for (int n = 0; n < 2; ++n) {
        const int c = n_base + n * 16 + cl;
        b1v[n] = b1[c]; b2v[n] = b2[c];
        gv[n]  = gam[c]; bv[n] = bet[c];
    }

    const int ntiles = (N_NODES + 63) / 64;
    for (int tile = blockIdx.x; tile < ntiles; tile += gridDim.x) {
        const int base = tile * 64;

        // ---- gather (contiguous rows; f32 -> bf16) ----
        {
            const int ch = tid & 15;
            const int r0 = tid >> 4;
#pragma unroll
            for (int gp = 0; gp < 4; ++gp) {
                const int row = gp * 16 + r0;
                const int rx = row & 7;
                int gn = base + row;
                if (gn >= N_NODES) gn = N_NODES - 1;
                uint4* dst = (uint4*)x_lds + row * 16;
                dst[ch ^ rx]          = pack8(node + (size_t)gn * 128 + ch * 8);
                dst[1024 + (ch ^ rx)] = pack8(aggr + (size_t)gn * 128 + ch * 8);
            }
        }
        __syncthreads();  // A

        // ---- layer 1: [64,256] x [256,128] ----
        f32x4 acc[4][2];
#pragma unroll
        for (int m = 0; m < 4; ++m)
#pragma unroll
            for (int n = 0; n < 2; ++n)
#pragma unroll
                for (int r = 0; r < 4; ++r) acc[m][n][r] = 0.f;

        uint4 wreg[10][2];
#pragma unroll
        for (int kb = 0; kb < 2; ++kb)
#pragma unroll
            for (int n = 0; n < 2; ++n)
                wreg[kb][n] = w1p[(kb * 8 + w * 2 + n) * 64 + lane];

#pragma unroll
        for (int kb = 0; kb < 8; ++kb) {
            if (kb + 2 < 8) {
#pragma unroll
                for (int n = 0; n < 2; ++n)
                    wreg[kb + 2][n] = w1p[((kb + 2) * 8 + w * 2 + n) * 64 + lane];
            }
            const int p = kb >> 2, k2 = kb & 3;
            bf16x8 a[4];
#pragma unroll
            for (int m = 0; m < 4; ++m) {
                const int row = m * 16 + cl;
                a[m] = __builtin_bit_cast(bf16x8,
                    ((const uint4*)x_lds)[p * 1024 + row * 16 + ((k2 * 4 + q) ^ (row & 7))]);
            }
#pragma unroll
            for (int m = 0; m < 4; ++m)
#pragma unroll
                for (int n = 0; n < 2; ++n)
                    acc[m][n] = __builtin_amdgcn_mfma_f32_16x16x32_bf16(
                        a[m], __builtin_bit_cast(bf16x8, wreg[kb][n]), acc[m][n], 0, 0, 0);
        }

        uint4 w2reg[4][2];
#pragma unroll
        for (int kb = 0; kb < 4; ++kb)
#pragma unroll
            for (int n = 0; n < 2; ++n)
                w2reg[kb][n] = w2p[(kb * 8 + w * 2 + n) * 64 + lane];

        __syncthreads();  // B: done reading part1 before h overlay

        {
            __bf16* hb = (__bf16*)(x_lds + 8192);  // part1 region
#pragma unroll
            for (int m = 0; m < 4; ++m)
#pragma unroll
                for (int n = 0; n < 2; ++n)
#pragma unroll
                    for (int r = 0; r < 4; ++r) {
                        const int row = m * 16 + q * 4 + r;
                        const int col = n_base + n * 16 + cl;
                        hb[row * 128 + (((col >> 3) ^ (row & 7)) << 3) + (col & 7)] =
                            (__bf16)fmaxf(acc[m][n][r] + b1v[n], 0.f);
                    }
        }
        __syncthreads();  // C

        // ---- layer 2 ----
#pragma unroll
        for (int m = 0; m < 4; ++m)
#pragma unroll
            for (int n = 0; n < 2; ++n)
#pragma unroll
                for (int r = 0; r < 4; ++r) acc[m][n][r] = 0.f;
#pragma unroll
        for (int kb = 0; kb < 4; ++kb) {
            bf16x8 a[4];
#pragma unroll
            for (int m = 0; m < 4; ++m) {
                const int row = m * 16 + cl;
                a[m] = __builtin_bit_cast(bf16x8,
                    ((const uint4*)x_lds)[1024 + row * 16 + ((kb * 4 + q) ^ (row & 7))]);
            }
#pragma unroll
            for (int m = 0; m < 4; ++m)
#pragma unroll
                for (int n = 0; n < 2; ++n)
                    acc[m][n] = __builtin_amdgcn_mfma_f32_16x16x32_bf16(
                        a[m], __builtin_bit_cast(bf16x8, w2reg[kb][n]), acc[m][n], 0, 0, 0);
        }
#pragma unroll
        for (int m = 0; m < 4; ++m)
#pragma unroll
            for (int n = 0; n < 2; ++n)
#pragma unroll
                for (int r = 0; r < 4; ++r)
                    acc[m][n][r] = fmaxf(acc[m][n][r] + b2v[n], 0.f);

#pragma unroll
        for (int m = 0; m < 4; ++m)
#pragma unroll
            for (int r = 0; r < 4; ++r) {
                float s  = acc[m][0][r] + acc[m][1][r];
                float ss = acc[m][0][r] * acc[m][0][r] + acc[m][1][r] * acc[m][1][r];
#pragma unroll
                for (int off = 1; off < 16; off <<= 1) {
                    s  += __shfl_xor(s, off, 64);
                    ss += __shfl_xor(ss, off, 64);
                }
                if (cl == 0) part[w * 64 + m * 16 + q * 4 + r] = make_float2(s, ss);
            }
        __syncthreads();  // D
        if (tid < 64) {
            float s = 0.f, ss = 0.f;
#pragma unroll
            for (int ww = 0; ww < 4; ++ww) { const float2 pp = part[ww * 64 + tid]; s += pp.x; ss += pp.y; }
            const float mu = s * (1.f / 128.f);
            const float var = ss * (1.f / 128.f) - mu * mu;
            muv[tid] = mu;
            rsv[tid] = rsqrtf(var + LN_EPS);
        }
        __syncthreads();  // E

        // ---- LN + residual(part0) + guarded f32 writeout ----
#pragma unroll
        for (int m = 0; m < 4; ++m)
#pragma unroll
            for (int r = 0; r < 4; ++r) {
                const int row = m * 16 + q * 4 + r;
                if (base + row < N_NODES) {
                    const float mu = muv[row];
                    const float rs = rsv[row];
                    float* orow = nout + (size_t)(base + row) * 128;
#pragma unroll
                    for (int n = 0; n < 2; ++n) {
                        const int col = n_base + n * 16 + cl;
                        const float ln = (acc[m][n][r] - mu) * rs * gv[n] + bv[n];
                        const float e = (float)((__bf16*)x_lds)[row * 128 + (((col >> 3) ^ (row & 7)) << 3) + (col & 7)];
                        orow[col] = ln + e;
                    }
                }
            }
        __syncthreads();  // F
    }
}

extern "C" void kernel_launch(void* const* d_in, const int* in_sizes, int n_in,
                              void* d_out, int out_size, void* d_ws, size_t ws_size,
                              hipStream_t stream) {
    (void)in_sizes; (void)n_in; (void)out_size;
    const float* node = (const float*)d_in[0];
    const float* elat = (const float*)d_in[1];
    const int* senders = (const int*)d_in[2];
    const int* receivers = (const int*)d_in[3];
    const float* me_w1 = (const float*)d_in[4];
    const float* me_b1 = (const float*)d_in[5];
    const float* me_w2 = (const float*)d_in[6];
    const float* me_b2 = (const float*)d_in[7];
    const float* me_g  = (const float*)d_in[8];
    const float* me_be = (const float*)d_in[9];
    const float* nf_w1 = (const float*)d_in[10];
    const float* nf_b1 = (const float*)d_in[11];
    const float* nf_w2 = (const float*)d_in[12];
    const float* nf_b2 = (const float*)d_in[13];
    const float* nf_g  = (const float*)d_in[14];
    const float* nf_be = (const float*)d_in[15];

    float* out_nodes = (float*)d_out;
    float* out_edges = out_nodes + (size_t)N_NODES * 128;
    float* aggr = (float*)d_ws;
    const size_t aggr_bytes = (size_t)N_NODES * 128 * sizeof(float);
    uint4* wpack = (uint4*)((char*)d_ws + aggr_bytes);
    if (ws_size < aggr_bytes + 14336 * sizeof(uint4)) return;

    hipMemsetAsync(aggr, 0, aggr_bytes, stream);
    pack_weights<<<56, 256, 0, stream>>>(me_w1, me_w2, nf_w1, nf_w2, wpack);
    edge_mlp_kernel<<<768, 256, 0, stream>>>(node, elat, senders, receivers,
                                             me_b1, me_b2, me_g, me_be,
                                             wpack, wpack + 6144,
                                             out_edges, aggr);
    node_mlp_kernel<<<782, 256, 0, stream>>>(node, aggr,
                                             nf_b1, nf_b2, nf_g, nf_be,
                                             wpack + 8192, wpack + 12288,
                                             out_nodes);
}